// Round 1
// baseline (268.425 us; speedup 1.0000x reference)
//
#include <hip/hip_runtime.h>

// Problem constants (fixed by setup_inputs in the reference)
#define BB 64
#define TT 262144
#define CC 3
#define KK 16384
#define HH 32
#define WIN 2

#define NPHASE 8     // batches per XCD, swept sequentially so each 3MB slab is L2-resident
#define NBLK   512   // 8 XCDs x 64 blocks (bid&7 -> XCD round-robin, m09-verified idiom)
#define NT     256

// 16B vector with only 4B alignment requirement: window base is 12B-strided.
typedef float f32x4 __attribute__((ext_vector_type(4), aligned(4)));

__device__ __forceinline__ void pool_generic(const float* __restrict__ xb, int idx,
                                             float& p0, float& p1, float& p2) {
    float s0 = 0.f, s1 = 0.f, s2 = 0.f, cnt = 0.f;
#pragma unroll
    for (int o = -WIN; o <= WIN; ++o) {
        const int pos = idx + o;
        if (pos >= 0 && pos < TT) {
            const float* p = xb + (size_t)pos * CC;
            s0 += p[0]; s1 += p[1]; s2 += p[2]; cnt += 1.f;
        }
    }
    const float rc = 1.f / cnt;
    p0 = s0 * rc; p1 = s1 * rc; p2 = s2 * rc;
}

__global__ __launch_bounds__(NT) void refiner_kernel(
    const float* __restrict__ x,        // [B,T,C]
    const int*   __restrict__ ids,      // [B,K]
    const float* __restrict__ W1,       // [C,H]  (uniform reads -> s_load)
    const float* __restrict__ b1,       // [H]
    const float* __restrict__ W2,       // [H]
    const float* __restrict__ b2,       // [1]
    float*       __restrict__ out)      // [B,K]
{
    const int t   = threadIdx.x;
    const int bid = blockIdx.x;
    const int xcd = bid & 7;            // dispatch round-robins XCDs by bid%8
    const int lo  = bid >> 3;           // local block on this XCD [0,64)
    const int col = lo * NT + t;        // position within one batch row [0,16384)

    // Prefetch this thread's id for all 8 phases. XCD x owns batches 8x..8x+7;
    // per phase ALL 64 blocks of the XCD hit the SAME 3MB slab -> fits 4MB L2,
    // so the ~1.57x average line reuse becomes L2 hits instead of HBM refetch.
    int mid[NPHASE];
#pragma unroll
    for (int p = 0; p < NPHASE; ++p)
        mid[p] = ids[(size_t)(xcd * NPHASE + p) * KK + col];

    // Stage phase 0's window (4 overlapping dwordx4, 60B useful).
    f32x4 a0, a1, a2, a3;
    {
        const int i0 = mid[0];
        if (i0 >= WIN && i0 < TT - WIN) {
            const float* ba = x + (size_t)(xcd * NPHASE) * TT * CC
                                + (size_t)(i0 - WIN) * CC;
            a0 = *(const f32x4*)(ba);
            a1 = *(const f32x4*)(ba + 4);
            a2 = *(const f32x4*)(ba + 8);
            a3 = *(const f32x4*)(ba + 11);
        }
    }

    const float bias2 = b2[0];

    // Fully unrolled phase loop (rule #20: static indexing of mid[] and the
    // double-buffered window regs -> no scratch). 1-phase-ahead pipeline:
    // stage(p+1) issues before consume(p), so the vmcnt wait for phase p's
    // data happened a whole phase (~2.5us of HBM time) earlier.
#pragma unroll
    for (int p = 0; p < NPHASE; ++p) {
        f32x4 n0, n1, n2, n3;
        if (p + 1 < NPHASE) {               // compile-time after unroll
            const int in = mid[p + 1];
            if (in >= WIN && in < TT - WIN) {
                const float* bb = x + (size_t)(xcd * NPHASE + p + 1) * TT * CC
                                    + (size_t)(in - WIN) * CC;
                n0 = *(const f32x4*)(bb);
                n1 = *(const f32x4*)(bb + 4);
                n2 = *(const f32x4*)(bb + 8);
                n3 = *(const f32x4*)(bb + 11);
            }
        }

        // Consume phase p: pooled means from the staged regs.
        const int id = mid[p];
        float p0, p1, p2;
        if (id >= WIN && id < TT - WIN) {
            // rows: r0=d0..2 r1=d3..5 r2=d6..8 r3=d9..11 r4=d12..14
            p0 = (a0.x + a0.w + a1.z + a2.y + a3.y) * 0.2f;
            p1 = (a0.y + a1.x + a1.w + a2.z + a3.z) * 0.2f;
            p2 = (a0.z + a1.y + a2.x + a2.w + a3.w) * 0.2f;
        } else {
            // ~16 of 1M ids; rare divergence, scalar re-load is fine.
            pool_generic(x + (size_t)(xcd * NPHASE + p) * TT * CC, id, p0, p1, p2);
        }

        // MLP: weight addresses are wave-uniform -> s_load via scalar cache.
        float acc = bias2;
#pragma unroll
        for (int j = 0; j < HH; ++j) {
            float h = fmaf(p0, W1[j],
                      fmaf(p1, W1[HH + j],
                      fmaf(p2, W1[2 * HH + j], b1[j])));
            acc = fmaf(fmaxf(h, 0.f), W2[j], acc);
        }

        out[(size_t)(xcd * NPHASE + p) * KK + col] = acc;   // coalesced dword

        a0 = n0; a1 = n1; a2 = n2; a3 = n3;  // rename, no real movs after unroll
    }
}

extern "C" void kernel_launch(void* const* d_in, const int* in_sizes, int n_in,
                              void* d_out, int out_size, void* d_ws, size_t ws_size,
                              hipStream_t stream) {
    const float* x   = (const float*)d_in[0];
    const int*   ids = (const int*)  d_in[1];
    const float* W1  = (const float*)d_in[2];
    const float* b1  = (const float*)d_in[3];
    const float* W2  = (const float*)d_in[4];
    const float* b2  = (const float*)d_in[5];
    float* out = (float*)d_out;

    refiner_kernel<<<NBLK, NT, 0, stream>>>(x, ids, W1, b1, W2, b2, out);
}